// Round 1
// baseline (550.161 us; speedup 1.0000x reference)
//
#include <hip/hip_runtime.h>
#include <stdint.h>

#define N_PTS 100000
#define K_CL  256
#define F_DIM 256

#define BN    128      // points per block
#define FC    32       // features per LDS stage
#define XPAD  36       // x-tile row stride (floats): 144B = 9 quads -> quad = row%8
#define CPAD  36       // c-tile row stride

// ---------------- Kernel A: c_sq + init best ----------------
__global__ void init_csq_kernel(const float* __restrict__ c,
                                unsigned long long* __restrict__ best,
                                float* __restrict__ csq) {
    int k = blockIdx.x;          // one cluster per block (64-thread wave)
    int lane = threadIdx.x;
    const float* row = c + k * F_DIM;
    float s = 0.f;
    #pragma unroll
    for (int f = lane; f < F_DIM; f += 64) { float v = row[f]; s = fmaf(v, v, s); }
    #pragma unroll
    for (int off = 32; off; off >>= 1) s += __shfl_down(s, off, 64);
    if (lane == 0) { csq[k] = s; best[k] = 0xFFFFFFFFFFFFFFFFULL; }
}

// ---------------- Kernel B: main distance + argmin ----------------
__global__ __launch_bounds__(256, 2)
void cluster_argmin_kernel(const float* __restrict__ x,
                           const float* __restrict__ c,
                           const float* __restrict__ csq,
                           unsigned long long* __restrict__ best) {
    __shared__ float xt[BN][XPAD];            // 18.4 KB
    __shared__ float ct[K_CL][CPAD];          // 36.9 KB
    __shared__ unsigned long long shb[K_CL];  // 2 KB

    const int tid = threadIdx.x;
    const int cg  = tid & 15;   // cluster group: clusters cg + 16*j
    const int pg  = tid >> 4;   // point group (0..15): points pg + 16*i
    const int n0  = blockIdx.x * BN;

    shb[tid] = 0xFFFFFFFFFFFFFFFFULL;

    float acc[8][16];
    #pragma unroll
    for (int i = 0; i < 8; ++i)
        #pragma unroll
        for (int j = 0; j < 16; ++j) acc[i][j] = 0.f;
    float xsq[8];
    #pragma unroll
    for (int i = 0; i < 8; ++i) xsq[i] = 0.f;

    for (int s = 0; s < 8; ++s) {            // 8 stages of FC=32 features
        const int f0 = s * FC;
        __syncthreads();                     // protect previous-stage reads
        // stage x tile: 128 rows x 32 floats = 1024 float4, 4 per thread
        #pragma unroll
        for (int q = 0; q < 4; ++q) {
            int fi  = q * 256 + tid;         // 0..1023
            int row = fi >> 3;
            int c4  = fi & 7;
            int n   = n0 + row;
            float4 v = make_float4(0.f, 0.f, 0.f, 0.f);
            if (n < N_PTS)
                v = *(const float4*)(x + (size_t)n * F_DIM + f0 + c4 * 4);
            *(float4*)(&xt[row][c4 * 4]) = v;
        }
        // stage c tile: 256 rows x 32 floats = 2048 float4, 8 per thread
        #pragma unroll
        for (int q = 0; q < 8; ++q) {
            int fi  = q * 256 + tid;         // 0..2047
            int row = fi >> 3;
            int c4  = fi & 7;
            float4 v = *(const float4*)(c + (size_t)row * F_DIM + f0 + c4 * 4);
            *(float4*)(&ct[row][c4 * 4]) = v;
        }
        __syncthreads();

        #pragma unroll
        for (int f4 = 0; f4 < 8; ++f4) {
            float4 xv[8];
            #pragma unroll
            for (int i = 0; i < 8; ++i)
                xv[i] = *(const float4*)(&xt[pg + 16 * i][f4 * 4]);
            #pragma unroll
            for (int i = 0; i < 8; ++i) {
                xsq[i] = fmaf(xv[i].x, xv[i].x, xsq[i]);
                xsq[i] = fmaf(xv[i].y, xv[i].y, xsq[i]);
                xsq[i] = fmaf(xv[i].z, xv[i].z, xsq[i]);
                xsq[i] = fmaf(xv[i].w, xv[i].w, xsq[i]);
            }
            #pragma unroll
            for (int j = 0; j < 16; ++j) {
                float4 cv = *(const float4*)(&ct[cg + 16 * j][f4 * 4]);
                #pragma unroll
                for (int i = 0; i < 8; ++i) {
                    acc[i][j] = fmaf(xv[i].x, cv.x, acc[i][j]);
                    acc[i][j] = fmaf(xv[i].y, cv.y, acc[i][j]);
                    acc[i][j] = fmaf(xv[i].z, cv.z, acc[i][j]);
                    acc[i][j] = fmaf(xv[i].w, cv.w, acc[i][j]);
                }
            }
        }
    }

    // epilogue: d2 -> dist -> packed (distbits<<32 | n) -> per-cluster min
    #pragma unroll
    for (int j = 0; j < 16; ++j) {
        const int cl = cg + 16 * j;
        const float cs = csq[cl];
        unsigned long long bl = 0xFFFFFFFFFFFFFFFFULL;
        #pragma unroll
        for (int i = 0; i < 8; ++i) {
            int n = n0 + pg + 16 * i;
            float d2 = fmaf(-2.f, acc[i][j], xsq[i] + cs);
            d2 = fmaxf(d2, 0.f);
            float d = sqrtf(d2);
            unsigned long long pk =
                ((unsigned long long)__float_as_uint(d) << 32) | (unsigned int)n;
            if (n < N_PTS && pk < bl) bl = pk;
        }
        atomicMin(&shb[cl], bl);
    }
    __syncthreads();
    atomicMin(&best[tid], shb[tid]);
}

// ---------------- Kernel C: gather winners ----------------
__global__ void gather_kernel(const float* __restrict__ x,
                              const unsigned long long* __restrict__ best,
                              float* __restrict__ out) {
    int k = blockIdx.x;
    unsigned int idx = (unsigned int)(best[k] & 0xFFFFFFFFULL);
    int t = threadIdx.x; // 64 threads, float4 each = 256 floats
    float4 v = *(const float4*)(x + (size_t)idx * F_DIM + t * 4);
    *(float4*)(out + (size_t)k * F_DIM + t * 4) = v;
}

extern "C" void kernel_launch(void* const* d_in, const int* in_sizes, int n_in,
                              void* d_out, int out_size, void* d_ws, size_t ws_size,
                              hipStream_t stream) {
    const float* x = (const float*)d_in[0];          // (1, N, F) f32
    const float* c = (const float*)d_in[1];          // (K, F)   f32
    float* out = (float*)d_out;                      // (1, K, F) f32

    unsigned long long* best = (unsigned long long*)d_ws;            // 2048 B
    float* csq = (float*)((char*)d_ws + K_CL * sizeof(unsigned long long)); // 1024 B

    init_csq_kernel<<<K_CL, 64, 0, stream>>>(c, best, csq);

    int nblocks = (N_PTS + BN - 1) / BN;   // 782
    cluster_argmin_kernel<<<nblocks, 256, 0, stream>>>(x, c, csq, best);

    gather_kernel<<<K_CL, 64, 0, stream>>>(x, best, out);
}

// Round 2
// 546.437 us; speedup vs baseline: 1.0068x; 1.0068x over previous
//
#include <hip/hip_runtime.h>
#include <stdint.h>

#define N_PTS 100000
#define K_CL  256
#define F_DIM 256

// ---------------- Kernel A: c_sq + init best ----------------
__global__ void init_csq_kernel(const float* __restrict__ c,
                                unsigned long long* __restrict__ best,
                                float* __restrict__ csq) {
    int k = blockIdx.x;          // one cluster per block (64-thread wave)
    int lane = threadIdx.x;
    const float* row = c + k * F_DIM;
    float s = 0.f;
    #pragma unroll
    for (int f = lane; f < F_DIM; f += 64) { float v = row[f]; s = fmaf(v, v, s); }
    #pragma unroll
    for (int off = 32; off; off >>= 1) s += __shfl_down(s, off, 64);
    if (lane == 0) { csq[k] = s; best[k] = 0xFFFFFFFFFFFFFFFFULL; }
}

// ---------------- Kernel B: main distance + argmin ----------------
// Block = 256 threads = 4 waves. All 4 waves process the SAME 64 points
// (one point per lane); wave w handles clusters [64*w, 64*w+64).
// Cluster data is wave-uniform -> scalar loads (s_load) feeding the SGPR
// operand of v_fmac_f32. No LDS, no barriers, no spills.
__global__ __launch_bounds__(256, 4)
void cluster_argmin_kernel(const float* __restrict__ x,
                           const float* __restrict__ c,
                           const float* __restrict__ csq,
                           unsigned long long* __restrict__ best) {
    const int tid  = threadIdx.x;
    const int lane = tid & 63;
    // wave id is wave-uniform by construction; readfirstlane makes the
    // compiler's uniformity analysis see it, unlocking s_load for c.
    const int w  = __builtin_amdgcn_readfirstlane(tid >> 6);
    const int kb = w * 64;

    const int n = blockIdx.x * 64 + lane;
    const bool valid = (n < N_PTS);
    const float* xrow = x + (size_t)(valid ? n : 0) * F_DIM;

    float acc[64];
    #pragma unroll
    for (int k = 0; k < 64; ++k) acc[k] = 0.f;
    float xsq = 0.f;

    #pragma unroll 1
    for (int f0 = 0; f0 < F_DIM; f0 += 32) {
        float4 xv[8];
        #pragma unroll
        for (int q = 0; q < 8; ++q)
            xv[q] = *(const float4*)(xrow + f0 + q * 4);

        #pragma unroll
        for (int q = 0; q < 8; ++q) {
            xsq = fmaf(xv[q].x, xv[q].x, xsq);
            xsq = fmaf(xv[q].y, xv[q].y, xsq);
            xsq = fmaf(xv[q].z, xv[q].z, xsq);
            xsq = fmaf(xv[q].w, xv[q].w, xsq);
        }

        const float* crow = c + (size_t)kb * F_DIM + f0;   // wave-uniform
        #pragma unroll
        for (int k = 0; k < 64; ++k) {
            const float* ck = crow + k * F_DIM;            // wave-uniform
            #pragma unroll
            for (int q = 0; q < 8; ++q) {
                acc[k] = fmaf(ck[q * 4 + 0], xv[q].x, acc[k]);
                acc[k] = fmaf(ck[q * 4 + 1], xv[q].y, acc[k]);
                acc[k] = fmaf(ck[q * 4 + 2], xv[q].z, acc[k]);
                acc[k] = fmaf(ck[q * 4 + 3], xv[q].w, acc[k]);
            }
        }
    }

    // Epilogue: d2 -> dist -> packed (distbits<<32 | n) -> 64-lane butterfly
    // min per cluster; cluster k's result is kept by lane k, then one
    // (filtered) global atomicMin per lane.
    unsigned long long keep = 0xFFFFFFFFFFFFFFFFULL;
    #pragma unroll 1
    for (int k = 0; k < 64; ++k) {
        const float cs = csq[kb + k];                      // wave-uniform
        float d2 = fmaf(-2.f, acc[k], xsq + cs);
        d2 = fmaxf(d2, 0.f);
        float d = sqrtf(d2);
        unsigned long long pk =
            ((unsigned long long)__float_as_uint(d) << 32) | (unsigned int)n;
        if (!valid) pk = 0xFFFFFFFFFFFFFFFFULL;
        #pragma unroll
        for (int off = 32; off; off >>= 1) {
            unsigned long long o = __shfl_xor(pk, off, 64);
            pk = (o < pk) ? o : pk;
        }
        if (lane == k) keep = pk;
    }
    // Filter: plain 8B load is atomic on this HW; stale values are only
    // ever >= current, so a conservative skip is safe.
    unsigned long long cur = best[kb + lane];
    if (keep < cur) atomicMin(&best[kb + lane], keep);
}

// ---------------- Kernel C: gather winners ----------------
__global__ void gather_kernel(const float* __restrict__ x,
                              const unsigned long long* __restrict__ best,
                              float* __restrict__ out) {
    int k = blockIdx.x;
    unsigned int idx = (unsigned int)(best[k] & 0xFFFFFFFFULL);
    int t = threadIdx.x; // 64 threads, float4 each = 256 floats
    float4 v = *(const float4*)(x + (size_t)idx * F_DIM + t * 4);
    *(float4*)(out + (size_t)k * F_DIM + t * 4) = v;
}

extern "C" void kernel_launch(void* const* d_in, const int* in_sizes, int n_in,
                              void* d_out, int out_size, void* d_ws, size_t ws_size,
                              hipStream_t stream) {
    const float* x = (const float*)d_in[0];          // (1, N, F) f32
    const float* c = (const float*)d_in[1];          // (K, F)   f32
    float* out = (float*)d_out;                      // (1, K, F) f32

    unsigned long long* best = (unsigned long long*)d_ws;            // 2048 B
    float* csq = (float*)((char*)d_ws + K_CL * sizeof(unsigned long long)); // 1024 B

    init_csq_kernel<<<K_CL, 64, 0, stream>>>(c, best, csq);

    int nblocks = (N_PTS + 63) / 64;   // 1563 blocks of 64 points
    cluster_argmin_kernel<<<nblocks, 256, 0, stream>>>(x, c, csq, best);

    gather_kernel<<<K_CL, 64, 0, stream>>>(x, best, out);
}

// Round 4
// 424.026 us; speedup vs baseline: 1.2975x; 1.2887x over previous
//
#include <hip/hip_runtime.h>
#include <stdint.h>

#define N_PTS 100000
#define K_CL  256
#define F_DIM 256

// ---------------- Kernel A: c_sq + init best ----------------
__global__ void init_csq_kernel(const float* __restrict__ c,
                                unsigned long long* __restrict__ best,
                                float* __restrict__ csq) {
    int k = blockIdx.x;          // one cluster per block (64-thread wave)
    int lane = threadIdx.x;
    const float* row = c + k * F_DIM;
    float s = 0.f;
    #pragma unroll
    for (int f = lane; f < F_DIM; f += 64) { float v = row[f]; s = fmaf(v, v, s); }
    #pragma unroll
    for (int off = 32; off; off >>= 1) s += __shfl_down(s, off, 64);
    if (lane == 0) { csq[k] = s; best[k] = 0xFFFFFFFFFFFFFFFFULL; }
}

// ---------------- Kernel B: main distance + argmin ----------------
// Block = 256 threads = 4 waves. All 4 waves process the SAME 64 points
// (one point per lane); wave w handles clusters [64*w, 64*w+64).
// Cluster data is wave-uniform -> scalar loads feeding the SGPR operand of
// v_fmac_f32. No LDS tiles, no barriers. ALL acc[] indices are compile-time
// static (round-2 lesson: one runtime index sent the whole array to scratch).
__global__ __launch_bounds__(256, 4)
void cluster_argmin_kernel(const float* __restrict__ x,
                           const float* __restrict__ c,
                           const float* __restrict__ csq,
                           unsigned long long* __restrict__ best) {
    const int tid  = threadIdx.x;
    const int lane = tid & 63;
    const int w  = __builtin_amdgcn_readfirstlane(tid >> 6);
    const int kb = w * 64;

    const int n = blockIdx.x * 64 + lane;
    const bool valid = (n < N_PTS);
    const float* xrow = x + (size_t)(valid ? n : 0) * F_DIM;

    float acc[64];
    #pragma unroll
    for (int k = 0; k < 64; ++k) acc[k] = 0.f;
    float xsq = 0.f;

    #pragma unroll 1
    for (int f0 = 0; f0 < F_DIM; f0 += 32) {
        float4 xv[8];
        #pragma unroll
        for (int q = 0; q < 8; ++q)
            xv[q] = *(const float4*)(xrow + f0 + q * 4);

        #pragma unroll
        for (int q = 0; q < 8; ++q) {
            xsq = fmaf(xv[q].x, xv[q].x, xsq);
            xsq = fmaf(xv[q].y, xv[q].y, xsq);
            xsq = fmaf(xv[q].z, xv[q].z, xsq);
            xsq = fmaf(xv[q].w, xv[q].w, xsq);
        }

        const float* crow = c + (size_t)kb * F_DIM + f0;   // wave-uniform
        #pragma unroll
        for (int k = 0; k < 64; ++k) {
            const float* ck = crow + k * F_DIM;            // wave-uniform
            #pragma unroll
            for (int q = 0; q < 8; ++q) {
                acc[k] = fmaf(ck[q * 4 + 0], xv[q].x, acc[k]);
                acc[k] = fmaf(ck[q * 4 + 1], xv[q].y, acc[k]);
                acc[k] = fmaf(ck[q * 4 + 2], xv[q].z, acc[k]);
                acc[k] = fmaf(ck[q * 4 + 3], xv[q].w, acc[k]);
            }
        }
    }

    // Epilogue: pack (distbits<<32 | n), then recursive-halving
    // transpose-reduce: fold cluster-index bit s against lane bit s.
    // After 5 folds + 1 cross-half min, lane l holds cluster kb+l's min.
    // Two 32-cluster halves keep peak register pressure ~110 VGPRs.
    // All array indices static; runtime decisions are value selects only.
    unsigned long long resA, resB;
    #pragma unroll
    for (int h = 0; h < 2; ++h) {
        unsigned long long a[32];
        #pragma unroll
        for (int k = 0; k < 32; ++k) {
            const int kk = h * 32 + k;
            const float cs = csq[kb + kk];                 // wave-uniform
            float d2 = fmaf(-2.f, acc[kk], xsq + cs);
            d2 = fmaxf(d2, 0.f);
            float d = sqrtf(d2);
            unsigned long long pk =
                ((unsigned long long)__float_as_uint(d) << 32) | (unsigned int)n;
            a[k] = valid ? pk : 0xFFFFFFFFFFFFFFFFULL;
        }
        #pragma unroll
        for (int s = 0; s < 5; ++s) {
            const int cnt = 16 >> s;
            const int bit = (lane >> s) & 1;
            #pragma unroll
            for (int j = 0; j < cnt; ++j) {
                unsigned long long lo = a[2 * j], hi = a[2 * j + 1];
                unsigned long long mine = bit ? hi : lo;
                unsigned long long send = bit ? lo : hi;
                unsigned long long theirs = __shfl_xor(send, 1 << s, 64);
                a[j] = (mine < theirs) ? mine : theirs;
            }
        }
        unsigned long long other = __shfl_xor(a[0], 32, 64);
        unsigned long long r = (a[0] < other) ? a[0] : other;
        if (h == 0) resA = r; else resB = r;
    }
    unsigned long long keep = (lane < 32) ? resA : resB;   // cluster kb+lane

    // Filter: plain 8B load is atomic; stale values only over-estimate.
    unsigned long long cur = best[kb + lane];
    if (keep < cur) atomicMin(&best[kb + lane], keep);
}

// ---------------- Kernel C: gather winners ----------------
__global__ void gather_kernel(const float* __restrict__ x,
                              const unsigned long long* __restrict__ best,
                              float* __restrict__ out) {
    int k = blockIdx.x;
    unsigned int idx = (unsigned int)(best[k] & 0xFFFFFFFFULL);
    int t = threadIdx.x; // 64 threads, float4 each = 256 floats
    float4 v = *(const float4*)(x + (size_t)idx * F_DIM + t * 4);
    *(float4*)(out + (size_t)k * F_DIM + t * 4) = v;
}

extern "C" void kernel_launch(void* const* d_in, const int* in_sizes, int n_in,
                              void* d_out, int out_size, void* d_ws, size_t ws_size,
                              hipStream_t stream) {
    const float* x = (const float*)d_in[0];          // (1, N, F) f32
    const float* c = (const float*)d_in[1];          // (K, F)   f32
    float* out = (float*)d_out;                      // (1, K, F) f32

    unsigned long long* best = (unsigned long long*)d_ws;            // 2048 B
    float* csq = (float*)((char*)d_ws + K_CL * sizeof(unsigned long long)); // 1024 B

    init_csq_kernel<<<K_CL, 64, 0, stream>>>(c, best, csq);

    int nblocks = (N_PTS + 63) / 64;   // 1563 blocks of 64 points
    cluster_argmin_kernel<<<nblocks, 256, 0, stream>>>(x, c, csq, best);

    gather_kernel<<<K_CL, 64, 0, stream>>>(x, best, out);
}

// Round 5
// 292.402 us; speedup vs baseline: 1.8815x; 1.4501x over previous
//
#include <hip/hip_runtime.h>
#include <stdint.h>

#define N_PTS 100000
#define K_CL  256
#define F_DIM 256

using bf16x8 = __attribute__((ext_vector_type(8))) short;
using f32x4  = __attribute__((ext_vector_type(4))) float;

// RNE f32 -> bf16 bits (finite inputs only; avoids header API uncertainty)
__device__ __forceinline__ unsigned short f32_to_bf16_rne(float f) {
    unsigned u = __float_as_uint(f);
    unsigned r = u + 0x7FFFu + ((u >> 16) & 1u);
    return (unsigned short)(r >> 16);
}

// ---------------- Kernel A: split c into bf16 hi/lo, csq, init best ------
__global__ void prep_kernel(const float* __restrict__ c,
                            unsigned short* __restrict__ ch,
                            unsigned short* __restrict__ cl,
                            float* __restrict__ csq,
                            unsigned long long* __restrict__ best) {
    const int k = blockIdx.x;      // one cluster per 64-thread block
    const int lane = threadIdx.x;
    float4 v = *(const float4*)(c + (size_t)k * F_DIM + lane * 4);

    ushort4 h, l;
    {
        float e[4] = {v.x, v.y, v.z, v.w};
        unsigned short hh[4], ll[4];
        #pragma unroll
        for (int i = 0; i < 4; ++i) {
            hh[i] = f32_to_bf16_rne(e[i]);
            float hf = __uint_as_float((unsigned)hh[i] << 16);
            ll[i] = f32_to_bf16_rne(e[i] - hf);
        }
        h = make_ushort4(hh[0], hh[1], hh[2], hh[3]);
        l = make_ushort4(ll[0], ll[1], ll[2], ll[3]);
    }
    *(ushort4*)(ch + (size_t)k * F_DIM + lane * 4) = h;
    *(ushort4*)(cl + (size_t)k * F_DIM + lane * 4) = l;

    float s = v.x * v.x;
    s = fmaf(v.y, v.y, s);
    s = fmaf(v.z, v.z, s);
    s = fmaf(v.w, v.w, s);
    #pragma unroll
    for (int off = 32; off; off >>= 1) s += __shfl_down(s, off, 64);
    if (lane == 0) { csq[k] = s; best[k] = 0xFFFFFFFFFFFFFFFFULL; }
}

// ---------------- Kernel B: MFMA distance + argmin -----------------------
// Block = 256 threads = 4 waves. Block covers 64 points x 256 clusters;
// wave w covers all 64 points x clusters [64w, 64w+64).
// mfma_f32_16x16x32_bf16 fragments: A(lane): row m = lane&15, k = 8*(lane>>4)+i
// (8 contiguous features); B(lane): col n = lane&15, same k layout.
// D: col = lane&15 (cluster), row = (lane>>4)*4 + reg (point).  [m89/m91]
__global__ __launch_bounds__(256, 2)
void cluster_argmin_kernel(const float* __restrict__ x,
                           const unsigned short* __restrict__ ch,
                           const unsigned short* __restrict__ cl,
                           const float* __restrict__ csq,
                           unsigned long long* __restrict__ best) {
    const int tid  = threadIdx.x;
    const int lane = tid & 63;
    const int w    = __builtin_amdgcn_readfirstlane(tid >> 6);
    const int kb   = w * 64;
    const int n0   = blockIdx.x * 64;
    const int r15  = lane & 15;     // row/col within 16-group
    const int kg   = lane >> 4;     // feature sub-block (0..3), 8 feats each

    // clamped per-pg x base pointers (tail rows duplicate row N-1; masked later)
    const float* xbase[4];
    #pragma unroll
    for (int pg = 0; pg < 4; ++pg) {
        int r = n0 + pg * 16 + r15;
        r = r < N_PTS ? r : N_PTS - 1;
        xbase[pg] = x + (size_t)r * F_DIM + kg * 8;
    }
    const unsigned short* cbh[4];
    const unsigned short* cbl[4];
    #pragma unroll
    for (int cg = 0; cg < 4; ++cg) {
        size_t off = (size_t)(kb + cg * 16 + r15) * F_DIM + kg * 8;
        cbh[cg] = ch + off;
        cbl[cg] = cl + off;
    }

    f32x4 acc[4][4];
    #pragma unroll
    for (int pg = 0; pg < 4; ++pg)
        #pragma unroll
        for (int cg = 0; cg < 4; ++cg)
            acc[pg][cg] = (f32x4){0.f, 0.f, 0.f, 0.f};
    float xsq_part[4] = {0.f, 0.f, 0.f, 0.f};  // point pg*16+r15, feats kg*8 slices

    #pragma unroll 2
    for (int f0 = 0; f0 < F_DIM; f0 += 32) {
        bf16x8 xh[4], xl[4];
        #pragma unroll
        for (int pg = 0; pg < 4; ++pg) {
            float4 v0 = *(const float4*)(xbase[pg] + f0);
            float4 v1 = *(const float4*)(xbase[pg] + f0 + 4);
            float e[8] = {v0.x, v0.y, v0.z, v0.w, v1.x, v1.y, v1.z, v1.w};
            #pragma unroll
            for (int i = 0; i < 8; ++i) {
                unsigned short hh = f32_to_bf16_rne(e[i]);
                float hf = __uint_as_float((unsigned)hh << 16);
                unsigned short ll = f32_to_bf16_rne(e[i] - hf);
                xh[pg][i] = (short)hh;
                xl[pg][i] = (short)ll;
                xsq_part[pg] = fmaf(e[i], e[i], xsq_part[pg]);
            }
        }
        bf16x8 bh[4], bl[4];
        #pragma unroll
        for (int cg = 0; cg < 4; ++cg) {
            bh[cg] = *(const bf16x8*)(cbh[cg] + f0);
            bl[cg] = *(const bf16x8*)(cbl[cg] + f0);
        }
        #pragma unroll
        for (int pg = 0; pg < 4; ++pg) {
            #pragma unroll
            for (int cg = 0; cg < 4; ++cg) {
                acc[pg][cg] = __builtin_amdgcn_mfma_f32_16x16x32_bf16(
                    xh[pg], bh[cg], acc[pg][cg], 0, 0, 0);
                acc[pg][cg] = __builtin_amdgcn_mfma_f32_16x16x32_bf16(
                    xh[pg], bl[cg], acc[pg][cg], 0, 0, 0);
                acc[pg][cg] = __builtin_amdgcn_mfma_f32_16x16x32_bf16(
                    xl[pg], bh[cg], acc[pg][cg], 0, 0, 0);
            }
        }
    }

    // xsq: reduce partials (4 lanes per point) and redistribute to D layout
    float xsq_e[4][4];
    #pragma unroll
    for (int pg = 0; pg < 4; ++pg) {
        float s = xsq_part[pg];
        s += __shfl_xor(s, 16, 64);
        s += __shfl_xor(s, 32, 64);           // full xsq of point pg*16+r15
        #pragma unroll
        for (int r = 0; r < 4; ++r)
            xsq_e[pg][r] = __shfl(s, (kg << 2) + r, 64);
    }

    // epilogue: pack (sqrt-dist bits << 32 | n), per-cluster min
    unsigned long long keep = 0xFFFFFFFFFFFFFFFFULL;
    #pragma unroll
    for (int cg = 0; cg < 4; ++cg) {
        const float cs = csq[kb + cg * 16 + r15];
        unsigned long long m = 0xFFFFFFFFFFFFFFFFULL;
        #pragma unroll
        for (int pg = 0; pg < 4; ++pg) {
            #pragma unroll
            for (int r = 0; r < 4; ++r) {
                int n = n0 + pg * 16 + (kg << 2) + r;
                float d2 = fmaf(-2.f, acc[pg][cg][r], xsq_e[pg][r] + cs);
                d2 = fmaxf(d2, 0.f);
                float d = sqrtf(d2);
                unsigned long long pk =
                    ((unsigned long long)__float_as_uint(d) << 32) | (unsigned)n;
                if (n >= N_PTS) pk = 0xFFFFFFFFFFFFFFFFULL;
                m = pk < m ? pk : m;
            }
        }
        unsigned long long o = __shfl_xor(m, 16, 64);
        m = o < m ? o : m;
        o = __shfl_xor(m, 32, 64);
        m = o < m ? o : m;                    // cluster (kb+cg*16+r15) min
        if (kg == cg) keep = m;               // lane owns cluster kb+lane
    }
    unsigned long long cur = best[kb + lane];
    if (keep < cur) atomicMin(&best[kb + lane], keep);
}

// ---------------- Kernel C: gather winners ----------------
__global__ void gather_kernel(const float* __restrict__ x,
                              const unsigned long long* __restrict__ best,
                              float* __restrict__ out) {
    int k = blockIdx.x;
    unsigned int idx = (unsigned int)(best[k] & 0xFFFFFFFFULL);
    int t = threadIdx.x; // 64 threads, float4 each = 256 floats
    float4 v = *(const float4*)(x + (size_t)idx * F_DIM + t * 4);
    *(float4*)(out + (size_t)k * F_DIM + t * 4) = v;
}

extern "C" void kernel_launch(void* const* d_in, const int* in_sizes, int n_in,
                              void* d_out, int out_size, void* d_ws, size_t ws_size,
                              hipStream_t stream) {
    const float* x = (const float*)d_in[0];          // (1, N, F) f32
    const float* c = (const float*)d_in[1];          // (K, F)   f32
    float* out = (float*)d_out;                      // (1, K, F) f32

    unsigned long long* best = (unsigned long long*)d_ws;                    // 2 KB
    float* csq = (float*)((char*)d_ws + K_CL * sizeof(unsigned long long)); // 1 KB

    // c bf16 hi/lo live in d_out (256 KB, exact fit); final gather overwrites.
    unsigned short* ch = (unsigned short*)d_out;
    unsigned short* cl = ch + (size_t)K_CL * F_DIM;

    prep_kernel<<<K_CL, 64, 0, stream>>>(c, ch, cl, csq, best);

    int nblocks = (N_PTS + 63) / 64;   // 1563 blocks of 64 points
    cluster_argmin_kernel<<<nblocks, 256, 0, stream>>>(x, ch, cl, csq, best);

    gather_kernel<<<K_CL, 64, 0, stream>>>(x, best, out);
}

// Round 6
// 210.881 us; speedup vs baseline: 2.6089x; 1.3866x over previous
//
#include <hip/hip_runtime.h>
#include <stdint.h>

#define N_PTS 100000
#define K_CL  256
#define F_DIM 256
#define LDSPAD 40   // row stride in shorts: 80B -> frag reads spread all 32 banks

using bf16x8 = __attribute__((ext_vector_type(8))) short;
using f32x4  = __attribute__((ext_vector_type(4))) float;
typedef unsigned long long u64;

// RNE f32 -> bf16 bits (finite inputs only)
__device__ __forceinline__ unsigned short f32_to_bf16_rne(float f) {
    unsigned u = __float_as_uint(f);
    unsigned r = u + 0x7FFFu + ((u >> 16) & 1u);
    return (unsigned short)(r >> 16);
}

// ---------------- Kernel A: split c into bf16 hi/lo, csq, init best ------
__global__ void prep_kernel(const float* __restrict__ c,
                            unsigned short* __restrict__ ch,
                            unsigned short* __restrict__ cl,
                            float* __restrict__ csq,
                            u64* __restrict__ best) {
    const int k = blockIdx.x;      // one cluster per 64-thread block
    const int lane = threadIdx.x;
    float4 v = *(const float4*)(c + (size_t)k * F_DIM + lane * 4);

    float e[4] = {v.x, v.y, v.z, v.w};
    unsigned short hh[4], ll[4];
    #pragma unroll
    for (int i = 0; i < 4; ++i) {
        hh[i] = f32_to_bf16_rne(e[i]);
        float hf = __uint_as_float((unsigned)hh[i] << 16);
        ll[i] = f32_to_bf16_rne(e[i] - hf);
    }
    *(ushort4*)(ch + (size_t)k * F_DIM + lane * 4) = make_ushort4(hh[0], hh[1], hh[2], hh[3]);
    *(ushort4*)(cl + (size_t)k * F_DIM + lane * 4) = make_ushort4(ll[0], ll[1], ll[2], ll[3]);

    float s = v.x * v.x;
    s = fmaf(v.y, v.y, s);
    s = fmaf(v.z, v.z, s);
    s = fmaf(v.w, v.w, s);
    #pragma unroll
    for (int off = 32; off; off >>= 1) s += __shfl_down(s, off, 64);
    if (lane == 0) { csq[k] = s; best[k] = 0xFFFFFFFFFFFFFFFFULL; }
}

// ---------------- Kernel B: MFMA distance + argmin -----------------------
// Block = 512 threads = 8 waves, covers 64 points x 256 clusters.
// Wave w: all 64 points x clusters [32w, 32w+32)  -> acc[4][2] f32x4 = 32 VGPR.
// x is split fp32->bf16 hi/lo cooperatively (4 elems/thread) into a
// double-buffered LDS tile; one barrier per 32-feature chunk.
// mfma_f32_16x16x32_bf16 D layout: col=lane&15 (cluster), row=(lane>>4)*4+reg
// (point) [m89/m91]; A/B fragments are 8 contiguous K per lane.
__global__ __launch_bounds__(512, 4)
void cluster_argmin_kernel(const float* __restrict__ x,
                           const unsigned short* __restrict__ ch,
                           const unsigned short* __restrict__ cl,
                           const float* __restrict__ csq,
                           u64* __restrict__ best) {
    __shared__ unsigned short xh_lds[2][64][LDSPAD];   // 10.24 KB
    __shared__ unsigned short xl_lds[2][64][LDSPAD];   // 10.24 KB
    __shared__ float xsq_lds[64];

    const int tid  = threadIdx.x;
    const int lane = tid & 63;
    const int w    = __builtin_amdgcn_readfirstlane(tid >> 6);
    const int kb   = w * 32;
    const int n0   = blockIdx.x * 64;
    const int r15  = lane & 15;
    const int kg   = lane >> 4;

    // converter role: thread -> (point cp, 4-feature chunk cc)
    const int cp = tid >> 3;          // 0..63
    const int cc = tid & 7;           // 0..7
    int nrow = n0 + cp; if (nrow > N_PTS - 1) nrow = N_PTS - 1;
    const float* xptr = x + (size_t)nrow * F_DIM + cc * 4;

    // c fragment pointers (cluster kb+cg*16+r15, feature sub-block kg*8)
    const unsigned short* cbh[2];
    const unsigned short* cbl[2];
    #pragma unroll
    for (int cg = 0; cg < 2; ++cg) {
        size_t off = (size_t)(kb + cg * 16 + r15) * F_DIM + kg * 8;
        cbh[cg] = ch + off;
        cbl[cg] = cl + off;
    }

    f32x4 acc[4][2];
    #pragma unroll
    for (int pg = 0; pg < 4; ++pg)
        #pragma unroll
        for (int cg = 0; cg < 2; ++cg)
            acc[pg][cg] = (f32x4){0.f, 0.f, 0.f, 0.f};
    float xsq_p = 0.f;

    float4 nxt = *(const float4*)(xptr);     // prefetch chunk 0
    #pragma unroll 1
    for (int it = 0; it < 8; ++it) {
        const int f0 = it * 32;
        // convert this thread's 4 elements
        unsigned short h4[4], l4[4];
        float e[4] = {nxt.x, nxt.y, nxt.z, nxt.w};
        #pragma unroll
        for (int i = 0; i < 4; ++i) {
            h4[i] = f32_to_bf16_rne(e[i]);
            float hf = __uint_as_float((unsigned)h4[i] << 16);
            l4[i] = f32_to_bf16_rne(e[i] - hf);
            xsq_p = fmaf(e[i], e[i], xsq_p);
        }
        if (it < 7) nxt = *(const float4*)(xptr + (it + 1) * 32);  // prefetch next

        *(ushort4*)&xh_lds[it & 1][cp][cc * 4] = make_ushort4(h4[0], h4[1], h4[2], h4[3]);
        *(ushort4*)&xl_lds[it & 1][cp][cc * 4] = make_ushort4(l4[0], l4[1], l4[2], l4[3]);

        // issue c-frag loads before the barrier so global latency overlaps it
        bf16x8 bh[2], bl[2];
        #pragma unroll
        for (int cg = 0; cg < 2; ++cg) {
            bh[cg] = *(const bf16x8*)(cbh[cg] + f0);
            bl[cg] = *(const bf16x8*)(cbl[cg] + f0);
        }
        __syncthreads();

        #pragma unroll
        for (int pg = 0; pg < 4; ++pg) {
            bf16x8 xh8 = *(const bf16x8*)&xh_lds[it & 1][pg * 16 + r15][kg * 8];
            bf16x8 xl8 = *(const bf16x8*)&xl_lds[it & 1][pg * 16 + r15][kg * 8];
            #pragma unroll
            for (int cg = 0; cg < 2; ++cg) {
                acc[pg][cg] = __builtin_amdgcn_mfma_f32_16x16x32_bf16(
                    xh8, bh[cg], acc[pg][cg], 0, 0, 0);
                acc[pg][cg] = __builtin_amdgcn_mfma_f32_16x16x32_bf16(
                    xh8, bl[cg], acc[pg][cg], 0, 0, 0);
                acc[pg][cg] = __builtin_amdgcn_mfma_f32_16x16x32_bf16(
                    xl8, bh[cg], acc[pg][cg], 0, 0, 0);
            }
        }
    }

    // xsq: reduce the 8 chunk-threads of each point (adjacent lanes), stash in LDS
    xsq_p += __shfl_xor(xsq_p, 1, 64);
    xsq_p += __shfl_xor(xsq_p, 2, 64);
    xsq_p += __shfl_xor(xsq_p, 4, 64);
    if (cc == 0) xsq_lds[cp] = xsq_p;
    __syncthreads();

    // epilogue: pack (sqrt-dist bits << 32 | n), per-cluster min
    u64 keep = 0xFFFFFFFFFFFFFFFFULL;
    #pragma unroll
    for (int cg = 0; cg < 2; ++cg) {
        const float cs = csq[kb + cg * 16 + r15];
        u64 m = 0xFFFFFFFFFFFFFFFFULL;
        #pragma unroll
        for (int pg = 0; pg < 4; ++pg) {
            #pragma unroll
            for (int r = 0; r < 4; ++r) {
                const int pl = pg * 16 + kg * 4 + r;   // point within block
                const int n  = n0 + pl;
                float d2 = fmaf(-2.f, acc[pg][cg][r], xsq_lds[pl] + cs);
                d2 = fmaxf(d2, 0.f);
                float d = sqrtf(d2);
                u64 pk = ((u64)__float_as_uint(d) << 32) | (unsigned)n;
                if (n >= N_PTS) pk = 0xFFFFFFFFFFFFFFFFULL;
                m = pk < m ? pk : m;
            }
        }
        u64 o = __shfl_xor(m, 16, 64); m = o < m ? o : m;
        o = __shfl_xor(m, 32, 64);     m = o < m ? o : m;   // cluster kb+cg*16+r15
        if (kg == cg) keep = m;                              // lane<32 owns kb+lane
    }
    if (lane < 32) {
        u64 cur = best[kb + lane];                 // filter: stale is only ever >=
        if (keep < cur) atomicMin(&best[kb + lane], keep);
    }
}

// ---------------- Kernel C: gather winners ----------------
__global__ void gather_kernel(const float* __restrict__ x,
                              const u64* __restrict__ best,
                              float* __restrict__ out) {
    int k = blockIdx.x;
    unsigned int idx = (unsigned int)(best[k] & 0xFFFFFFFFULL);
    int t = threadIdx.x; // 64 threads, float4 each = 256 floats
    float4 v = *(const float4*)(x + (size_t)idx * F_DIM + t * 4);
    *(float4*)(out + (size_t)k * F_DIM + t * 4) = v;
}

extern "C" void kernel_launch(void* const* d_in, const int* in_sizes, int n_in,
                              void* d_out, int out_size, void* d_ws, size_t ws_size,
                              hipStream_t stream) {
    const float* x = (const float*)d_in[0];          // (1, N, F) f32
    const float* c = (const float*)d_in[1];          // (K, F)   f32
    float* out = (float*)d_out;                      // (1, K, F) f32

    u64* best  = (u64*)d_ws;                                         // 2 KB
    float* csq = (float*)((char*)d_ws + K_CL * sizeof(u64));         // 1 KB

    // c bf16 hi/lo live in d_out (256 KB, exact fit); final gather overwrites.
    unsigned short* ch = (unsigned short*)d_out;
    unsigned short* cl = ch + (size_t)K_CL * F_DIM;

    prep_kernel<<<K_CL, 64, 0, stream>>>(c, ch, cl, csq, best);

    int nblocks = (N_PTS + 63) / 64;   // 1563 blocks of 64 points
    cluster_argmin_kernel<<<nblocks, 512, 0, stream>>>(x, ch, cl, csq, best);

    gather_kernel<<<K_CL, 64, 0, stream>>>(x, best, out);
}